// Round 1
// baseline (260.635 us; speedup 1.0000x reference)
//
#include <hip/hip_runtime.h>

typedef short  bf16x8v __attribute__((ext_vector_type(8)));
typedef float  f32x4   __attribute__((ext_vector_type(4)));

#define GLOBAL_AS(p) ((const __attribute__((address_space(1))) void*)(p))
#define LDS_AS(p)    ((__attribute__((address_space(3))) void*)(p))

// ---- monotonic float<->uint encoding for exact atomicMax on f32 ----
__device__ inline unsigned enc_f32(float f) {
  unsigned u = __float_as_uint(f);
  return (u & 0x80000000u) ? ~u : (u | 0x80000000u);
}
__device__ inline float dec_f32(unsigned e) {
  unsigned u = (e & 0x80000000u) ? (e & 0x7FFFFFFFu) : ~e;
  return __uint_as_float(u);
}
__device__ inline unsigned short f32_to_bf16(float f) {
  // round-to-nearest-even bf16
  unsigned u = __float_as_uint(f);
  unsigned r = (u + 0x7FFFu + ((u >> 16) & 1u)) >> 16;
  return (unsigned short)r;
}

// ---------------- global max reduction (exact, deterministic) ----------------
__global__ void max_reduce_kernel(const float* __restrict__ x, size_t n,
                                  unsigned* __restrict__ out_enc) {
  size_t tid0   = (size_t)blockIdx.x * blockDim.x + threadIdx.x;
  size_t stride = (size_t)gridDim.x * blockDim.x;
  float m = -3.0e38f;
  const float4* x4 = (const float4*)x;
  size_t n4 = n >> 2;
  for (size_t i = tid0; i < n4; i += stride) {
    float4 v = x4[i];
    m = fmaxf(m, fmaxf(fmaxf(v.x, v.y), fmaxf(v.z, v.w)));
  }
  for (size_t i = (n4 << 2) + tid0; i < n; i += stride) m = fmaxf(m, x[i]);
  // wave(64) reduce
  for (int off = 32; off; off >>= 1) m = fmaxf(m, __shfl_down(m, off));
  __shared__ float wmax[8];
  int lane = threadIdx.x & 63, wv = threadIdx.x >> 6;
  if (lane == 0) wmax[wv] = m;
  __syncthreads();
  if (threadIdx.x == 0) {
    float bm = wmax[0];
    int nw = blockDim.x >> 6;
    for (int w = 1; w < nw; ++w) bm = fmaxf(bm, wmax[w]);
    atomicMax(out_enc, enc_f32(bm));
  }
}

// ---------------- exp(x - max) -> bf16, contiguous ----------------
__global__ void expcvt_a_kernel(const float* __restrict__ x,
                                unsigned short* __restrict__ y, size_t n,
                                const unsigned* __restrict__ enc) {
  float mx = dec_f32(enc[0]);
  size_t tid0   = (size_t)blockIdx.x * blockDim.x + threadIdx.x;
  size_t stride = (size_t)gridDim.x * blockDim.x;
  const float4* x4 = (const float4*)x;
  size_t n4 = n >> 2;
  for (size_t i = tid0; i < n4; i += stride) {
    float4 v = x4[i];
    ushort4 o;
    o.x = f32_to_bf16(__expf(v.x - mx));
    o.y = f32_to_bf16(__expf(v.y - mx));
    o.z = f32_to_bf16(__expf(v.z - mx));
    o.w = f32_to_bf16(__expf(v.w - mx));
    ((ushort4*)y)[i] = o;
  }
}

// ------------- exp(w - max_w) -> bf16, transposed: Bt[n][d] -------------
__global__ void expcvt_wt_kernel(const float* __restrict__ w,
                                 unsigned short* __restrict__ bt,
                                 int D, int O,
                                 const unsigned* __restrict__ enc) {
  float mw = dec_f32(enc[1]);
  __shared__ unsigned short tile[32][33];
  int c0 = blockIdx.x * 32;   // O (col of w)
  int r0 = blockIdx.y * 32;   // D (row of w)
  int tx = threadIdx.x;       // 0..31
  int ty = threadIdx.y;       // 0..7
#pragma unroll
  for (int j = 0; j < 4; ++j) {
    int r = r0 + ty + j * 8;
    tile[ty + j * 8][tx] = f32_to_bf16(__expf(w[(size_t)r * O + c0 + tx] - mw));
  }
  __syncthreads();
#pragma unroll
  for (int j = 0; j < 4; ++j) {
    int outr = c0 + ty + j * 8;            // N index
    bt[(size_t)outr * D + r0 + tx] = tile[tx][ty + j * 8];
  }
}

// ---------------- bf16 MFMA GEMM with log-epilogue ----------------
// A   : [M][K] bf16 (exp_inputs)
// Bt  : [N][K] bf16 (exp_w transposed)
// out : [M][N] f32 = log(A@B) + max_in + max_w + bias[n]
#define BM 128
#define BN 128
#define BK 32

__global__ __launch_bounds__(256, 2) void gemm_log_kernel(
    const unsigned short* __restrict__ A, const unsigned short* __restrict__ Bt,
    const float* __restrict__ bias, const unsigned* __restrict__ maxes,
    float* __restrict__ out, int M, int N, int K) {
  __shared__ unsigned short Asm[BM * BK];
  __shared__ unsigned short Bsm[BN * BK];

  const int tid  = threadIdx.x;
  const int wave = tid >> 6;
  const int lane = tid & 63;
  const int wr = wave >> 1;       // 0..1 row-wave
  const int wc = wave & 1;        // 0..1 col-wave
  const int brow = blockIdx.y * BM;
  const int bcol = blockIdx.x * BN;

  // staging source coords: thread t loads 16B = 8 bf16 of one row
  const int srow = tid >> 2;            // 0..63
  const int scol = (tid & 3) * 8;       // bf16 offset within 32-wide K-slab
  const unsigned short* a_src = A  + (size_t)(brow + srow) * K + scol;
  const unsigned short* b_src = Bt + (size_t)(bcol + srow) * K + scol;
  // LDS destinations (wave-uniform base; lane*16B implicit)
  unsigned short* a_dst0 = &Asm[wave * 512];
  unsigned short* a_dst1 = &Asm[2048 + wave * 512];
  unsigned short* b_dst0 = &Bsm[wave * 512];
  unsigned short* b_dst1 = &Bsm[2048 + wave * 512];

  f32x4 acc[4][4];
#pragma unroll
  for (int m = 0; m < 4; ++m)
#pragma unroll
    for (int n = 0; n < 4; ++n) acc[m][n] = (f32x4)0.0f;

  const int r    = lane & 15;
  const int koff = (lane >> 4) * 8;

  for (int k0 = 0; k0 < K; k0 += BK) {
    __builtin_amdgcn_global_load_lds(GLOBAL_AS(a_src + k0),            LDS_AS(a_dst0), 16, 0, 0);
    __builtin_amdgcn_global_load_lds(GLOBAL_AS(a_src + k0 + 64 * (size_t)K), LDS_AS(a_dst1), 16, 0, 0);
    __builtin_amdgcn_global_load_lds(GLOBAL_AS(b_src + k0),            LDS_AS(b_dst0), 16, 0, 0);
    __builtin_amdgcn_global_load_lds(GLOBAL_AS(b_src + k0 + 64 * (size_t)K), LDS_AS(b_dst1), 16, 0, 0);
    __syncthreads();

    bf16x8v a[4], b[4];
#pragma unroll
    for (int m = 0; m < 4; ++m)
      a[m] = *(const bf16x8v*)&Asm[(wr * 64 + m * 16 + r) * BK + koff];
#pragma unroll
    for (int n = 0; n < 4; ++n)
      b[n] = *(const bf16x8v*)&Bsm[(wc * 64 + n * 16 + r) * BK + koff];
#pragma unroll
    for (int m = 0; m < 4; ++m)
#pragma unroll
      for (int n = 0; n < 4; ++n)
        acc[m][n] = __builtin_amdgcn_mfma_f32_16x16x32_bf16(a[m], b[n], acc[m][n], 0, 0, 0);
    __syncthreads();
  }

  // epilogue: log + (max_in + max_w) + bias
  const float addc = dec_f32(maxes[0]) + dec_f32(maxes[1]);
#pragma unroll
  for (int m = 0; m < 4; ++m) {
    int row = brow + wr * 64 + m * 16 + (lane >> 4) * 4;
#pragma unroll
    for (int n = 0; n < 4; ++n) {
      int col = bcol + wc * 64 + n * 16 + (lane & 15);
      float bv = bias[col];
#pragma unroll
      for (int q = 0; q < 4; ++q) {
        out[(size_t)(row + q) * N + col] = __logf(acc[m][n][q]) + addc + bv;
      }
    }
  }
}

extern "C" void kernel_launch(void* const* d_in, const int* in_sizes, int n_in,
                              void* d_out, int out_size, void* d_ws, size_t ws_size,
                              hipStream_t stream) {
  const float* inputs = (const float*)d_in[0];
  const float* w      = (const float*)d_in[1];
  const float* bias   = (const float*)d_in[2];
  float* out = (float*)d_out;

  const int O = in_sizes[2];                 // 2048
  const int D = in_sizes[1] / O;             // 2048
  const size_t MD = (size_t)in_sizes[0];     // M*D
  const int M = (int)(MD / (size_t)D);       // 16384

  unsigned* maxes = (unsigned*)d_ws;
  unsigned short* Abf  = (unsigned short*)((char*)d_ws + 256);
  unsigned short* Btbf = (unsigned short*)((char*)d_ws + 256 + MD * 2);

  hipMemsetAsync(maxes, 0, 8, stream);

  max_reduce_kernel<<<2048, 256, 0, stream>>>(inputs, MD, maxes + 0);
  max_reduce_kernel<<<1024, 256, 0, stream>>>(w, (size_t)D * O, maxes + 1);

  expcvt_a_kernel<<<2048, 256, 0, stream>>>(inputs, Abf, MD, maxes);

  dim3 tg(O / 32, D / 32);
  expcvt_wt_kernel<<<tg, dim3(32, 8), 0, stream>>>(w, Btbf, D, O, maxes);

  dim3 grid(O / BN, M / BM);
  gemm_log_kernel<<<grid, 256, 0, stream>>>(Abf, Btbf, bias, maxes, out, M, O, D);
}

// Round 2
// 181.081 us; speedup vs baseline: 1.4393x; 1.4393x over previous
//
#include <hip/hip_runtime.h>

typedef short  bf16x8v __attribute__((ext_vector_type(8)));
typedef float  f32x4   __attribute__((ext_vector_type(4)));

#define GLOBAL_AS(p) ((const __attribute__((address_space(1))) void*)(p))
#define LDS_AS(p)    ((__attribute__((address_space(3))) void*)(p))
#define BAR()    __builtin_amdgcn_s_barrier()
#define LGKM0()  asm volatile("s_waitcnt lgkmcnt(0)" ::: "memory")
#define VMCNT2() asm volatile("s_waitcnt vmcnt(2)" ::: "memory")

__device__ inline unsigned short f32_to_bf16(float f) {
  unsigned u = __float_as_uint(f);
  unsigned r = (u + 0x7FFFu + ((u >> 16) & 1u)) >> 16;
  return (unsigned short)r;
}

// ---------------- exp(x) -> bf16, contiguous [M][K] ----------------
__global__ void expcvt_a_kernel(const float* __restrict__ x,
                                unsigned short* __restrict__ y, size_t n) {
  size_t tid0   = (size_t)blockIdx.x * blockDim.x + threadIdx.x;
  size_t stride = (size_t)gridDim.x * blockDim.x;
  const float4* x4 = (const float4*)x;
  size_t n4 = n >> 2;
  for (size_t i = tid0; i < n4; i += stride) {
    float4 v = x4[i];
    ushort4 o;
    o.x = f32_to_bf16(__expf(v.x));
    o.y = f32_to_bf16(__expf(v.y));
    o.z = f32_to_bf16(__expf(v.z));
    o.w = f32_to_bf16(__expf(v.w));
    ((ushort4*)y)[i] = o;
  }
}

// ------------- exp(w) -> bf16, transposed: Bt[n][d] -------------
__global__ void expcvt_wt_kernel(const float* __restrict__ w,
                                 unsigned short* __restrict__ bt,
                                 int D, int O) {
  __shared__ unsigned short tile[32][33];
  int c0 = blockIdx.x * 32;   // O (col of w)
  int r0 = blockIdx.y * 32;   // D (row of w)
  int tx = threadIdx.x;       // 0..31
  int ty = threadIdx.y;       // 0..7
#pragma unroll
  for (int j = 0; j < 4; ++j) {
    int r = r0 + ty + j * 8;
    tile[ty + j * 8][tx] = f32_to_bf16(__expf(w[(size_t)r * O + c0 + tx]));
  }
  __syncthreads();
#pragma unroll
  for (int j = 0; j < 4; ++j) {
    int outr = c0 + ty + j * 8;            // N index
    bt[(size_t)outr * D + r0 + tx] = tile[tx][ty + j * 8];
  }
}

// ---------------- 256x256 8-phase bf16 MFMA GEMM, log+bias epilogue ----------------
// A   : [M][K] bf16 (exp_inputs)     Bt : [N][K] bf16 (exp_w transposed)
// out : [M][N] f32 = log(A@B) + bias[n]
// 512 threads = 8 waves (2 Mrow x 4 Ncol), per-wave C tile 128x64.
// LDS 128 KiB: slot s: A at s*65536 (2 halves of [128][64]), B at s*65536+32768.
// XOR swizzle: colb ^= (row&7)<<4 (involution; applied on pre-swizzled
// global_load_lds source AND on ds_read addresses).

#define LOAD_A4(PTR, MOFF)                                                  \
  _Pragma("unroll") for (int mm = 0; mm < 4; ++mm) {                        \
    aF[mm][0] = *(const bf16x8v*)((PTR) + (MOFF + mm) * 2048 + cb0);        \
    aF[mm][1] = *(const bf16x8v*)((PTR) + (MOFF + mm) * 2048 + cb1);        \
  }
#define LOAD_B2(DST, PTR, NOFF)                                             \
  _Pragma("unroll") for (int nn = 0; nn < 2; ++nn) {                        \
    DST[nn][0] = *(const bf16x8v*)((PTR) + (NOFF + nn) * 2048 + cb0);       \
    DST[nn][1] = *(const bf16x8v*)((PTR) + (NOFF + nn) * 2048 + cb1);       \
  }
#define MFMA_Q(MB, NB, BARR)                                                \
  _Pragma("unroll") for (int mm = 0; mm < 4; ++mm)                          \
  _Pragma("unroll") for (int nn = 0; nn < 2; ++nn)                          \
  _Pragma("unroll") for (int ks = 0; ks < 2; ++ks)                          \
    acc[MB + mm][NB + nn] = __builtin_amdgcn_mfma_f32_16x16x32_bf16(        \
        aF[mm][ks], BARR[nn][ks], acc[MB + mm][NB + nn], 0, 0, 0);

__global__ __launch_bounds__(512, 2) void gemm8_log_kernel(
    const unsigned short* __restrict__ A, const unsigned short* __restrict__ Bt,
    const float* __restrict__ bias, float* __restrict__ out,
    int M, int N, int K) {
  __shared__ char lds[131072];

  const int tid  = threadIdx.x;
  const int wid  = tid >> 6, lane = tid & 63;
  const int wr   = wid >> 2, wc = wid & 3;
  const int r    = lane & 15, lh = lane >> 4;
  const int NT   = K >> 6;        // number of 64-wide K tiles (32)
  const int NIT  = NT >> 1;       // iterations (2 tiles each)
  const size_t Kb = (size_t)K * 2;

  // XCD-aware bijective swizzle (gridDim.x % 8 == 0 here: 512)
  const int cpx = gridDim.x >> 3;
  const int v   = (blockIdx.x & 7) * cpx + (blockIdx.x >> 3);
  const int nbn = N >> 8;
  const int bm  = v / nbn, bn = v % nbn;
  const int brow = bm << 8, bcol = bn << 8;

  // swizzled column-byte offsets for ds_read_b128 (row&7 == r&7 always)
  const int swz = (r & 7) << 4;
  const int cb0 = (lh * 16) ^ swz;        // ks = 0
  const int cb1 = cb0 ^ 64;               // ks = 1

  const char* pA0 = lds + wr * 16384 + r * 128;
  const char* pA1 = pA0 + 65536;
  const char* pB0 = lds + 32768 + (wc >> 1) * 16384 + ((wc & 1) * 64 + r) * 128;
  const char* pB1 = pB0 + 65536;

  // stage one 16KB half-tile (2 x global_load_lds of 16B x 512 threads)
  auto STAGE = [&](int t, int isB, int h) {
    const int tt = (t < NT) ? t : NT - 1;     // clamp keeps vmcnt ledger uniform
    const char* src = isB ? (const char*)Bt : (const char*)A;
    const int g0 = (isB ? bcol : brow) + h * 128;
    char* base = lds + (t & 1) * 65536 + isB * 32768 + h * 16384;
#pragma unroll
    for (int i = 0; i < 2; ++i) {
      const int o    = i * 8192 + tid * 16;
      const int row  = o >> 7;
      const int colb = (o & 127) ^ ((row & 7) << 4);   // inverse-swizzled source
      const char* g  = src + (size_t)(g0 + row) * Kb + (size_t)tt * 128 + colb;
      char* dst = base + i * 8192 + (tid >> 6) * 1024;  // wave-uniform base
      __builtin_amdgcn_global_load_lds(GLOBAL_AS(g), LDS_AS(dst), 16, 0, 0);
    }
  };

  f32x4 acc[8][4];
#pragma unroll
  for (int m = 0; m < 8; ++m)
#pragma unroll
    for (int n = 0; n < 4; ++n) acc[m][n] = (f32x4)0.0f;

  bf16x8v aF[4][2], b01[2][2], b23[2][2];

  // prologue: tile0 fully + tile1 A-h0  (5 half-tiles = 10 loads)
  STAGE(0, 0, 0); STAGE(0, 0, 1); STAGE(0, 1, 0); STAGE(0, 1, 1); STAGE(1, 0, 0);
  VMCNT2();   // retire tile0's 8 loads, keep 2 in flight
  BAR();

  for (int j = 0; j < NIT; ++j) {
    const int t1 = 2 * j + 1;
    // -- Phase 1 (slot0): reads A m0-3 + B n0-1 (12); stage A-h1(t1); Q(0,0)
    LOAD_A4(pA0, 0)
    LOAD_B2(b01, pB0, 0)
    STAGE(t1, 0, 1);
    BAR(); LGKM0();
    __builtin_amdgcn_s_setprio(1); MFMA_Q(0, 0, b01) __builtin_amdgcn_s_setprio(0);
    BAR();
    // -- Phase 2: reads B n2-3 (4); stage B-h0(t1); Q(0,1)
    LOAD_B2(b23, pB0, 2)
    STAGE(t1, 1, 0);
    BAR(); LGKM0();
    __builtin_amdgcn_s_setprio(1); MFMA_Q(0, 2, b23) __builtin_amdgcn_s_setprio(0);
    BAR();
    // -- Phase 3: reads A m4-7 (8); stage B-h1(t1); Q(1,1)
    LOAD_A4(pA0, 4)
    STAGE(t1, 1, 1);
    BAR(); LGKM0();
    __builtin_amdgcn_s_setprio(1); MFMA_Q(4, 2, b23) __builtin_amdgcn_s_setprio(0);
    BAR();
    // -- Phase 4: reads B n0-1 (4); stage A-h0(t+2); vmcnt(2); Q(1,0)
    LOAD_B2(b01, pB0, 0)
    STAGE(2 * j + 2, 0, 0);
    VMCNT2();
    BAR(); LGKM0();
    __builtin_amdgcn_s_setprio(1); MFMA_Q(4, 0, b01) __builtin_amdgcn_s_setprio(0);
    BAR();
    // -- Phase 5 (slot1): reads A m0-3 + B n0-1; stage A-h1(t+2); Q(0,0)
    LOAD_A4(pA1, 0)
    LOAD_B2(b01, pB1, 0)
    STAGE(2 * j + 2, 0, 1);
    BAR(); LGKM0();
    __builtin_amdgcn_s_setprio(1); MFMA_Q(0, 0, b01) __builtin_amdgcn_s_setprio(0);
    BAR();
    // -- Phase 6: reads B n2-3; stage B-h0(t+2); Q(0,1)
    LOAD_B2(b23, pB1, 2)
    STAGE(2 * j + 2, 1, 0);
    BAR(); LGKM0();
    __builtin_amdgcn_s_setprio(1); MFMA_Q(0, 2, b23) __builtin_amdgcn_s_setprio(0);
    BAR();
    // -- Phase 7: reads A m4-7; stage B-h1(t+2); Q(1,1)
    LOAD_A4(pA1, 4)
    STAGE(2 * j + 2, 1, 1);
    BAR(); LGKM0();
    __builtin_amdgcn_s_setprio(1); MFMA_Q(4, 2, b23) __builtin_amdgcn_s_setprio(0);
    BAR();
    // -- Phase 8: reads B n0-1; stage A-h0(t+3); vmcnt(2); Q(1,0)
    LOAD_B2(b01, pB1, 0)
    STAGE(2 * j + 3, 0, 0);
    VMCNT2();
    BAR(); LGKM0();
    __builtin_amdgcn_s_setprio(1); MFMA_Q(4, 0, b01) __builtin_amdgcn_s_setprio(0);
    BAR();
  }

  asm volatile("s_waitcnt vmcnt(0)" ::: "memory");

  // epilogue: out = log(acc) + bias
  const int crow0 = brow + wr * 128 + lh * 4;
  const int ccol0 = bcol + wc * 64 + r;
#pragma unroll
  for (int n = 0; n < 4; ++n) {
    const int col = ccol0 + n * 16;
    const float bv = bias[col];
#pragma unroll
    for (int m = 0; m < 8; ++m) {
      const int rowb = crow0 + m * 16;
#pragma unroll
      for (int q = 0; q < 4; ++q)
        out[(size_t)(rowb + q) * N + col] = __logf(acc[m][n][q]) + bv;
    }
  }
}

extern "C" void kernel_launch(void* const* d_in, const int* in_sizes, int n_in,
                              void* d_out, int out_size, void* d_ws, size_t ws_size,
                              hipStream_t stream) {
  const float* inputs = (const float*)d_in[0];
  const float* w      = (const float*)d_in[1];
  const float* bias   = (const float*)d_in[2];
  float* out = (float*)d_out;

  const int O = in_sizes[2];                 // 2048
  const int D = in_sizes[1] / O;             // 2048
  const size_t MD = (size_t)in_sizes[0];     // M*D
  const int M = (int)(MD / (size_t)D);       // 16384

  unsigned short* Abf  = (unsigned short*)d_ws;
  unsigned short* Btbf = (unsigned short*)((char*)d_ws + MD * 2);

  expcvt_a_kernel<<<2048, 256, 0, stream>>>(inputs, Abf, MD);

  dim3 tg(O / 32, D / 32);
  expcvt_wt_kernel<<<tg, dim3(32, 8), 0, stream>>>(w, Btbf, D, O);

  dim3 grid((M / 256) * (O / 256));
  gemm8_log_kernel<<<grid, 512, 0, stream>>>(Abf, Btbf, bias, out, M, O, D);
}

// Round 3
// 171.380 us; speedup vs baseline: 1.5208x; 1.0566x over previous
//
#include <hip/hip_runtime.h>

typedef short  bf16x8v __attribute__((ext_vector_type(8)));
typedef float  f32x4   __attribute__((ext_vector_type(4)));

#define GLOBAL_AS(p) ((const __attribute__((address_space(1))) void*)(p))
#define LDS_AS(p)    ((__attribute__((address_space(3))) void*)(p))
#define BAR()     __builtin_amdgcn_s_barrier()
#define LGKM0()   asm volatile("s_waitcnt lgkmcnt(0)" ::: "memory")
#define VMCNT(n)  asm volatile("s_waitcnt vmcnt(" #n ")" ::: "memory")
#define SP1       __builtin_amdgcn_s_setprio(1);
#define SP0       __builtin_amdgcn_s_setprio(0);

__device__ inline unsigned short f32_to_bf16(float f) {
  unsigned u = __float_as_uint(f);
  unsigned r = (u + 0x7FFFu + ((u >> 16) & 1u)) >> 16;
  return (unsigned short)r;
}

// ---------------- exp(x) -> bf16, contiguous [M][K] ----------------
__global__ void expcvt_a_kernel(const float* __restrict__ x,
                                unsigned short* __restrict__ y, size_t n) {
  size_t tid0   = (size_t)blockIdx.x * blockDim.x + threadIdx.x;
  size_t stride = (size_t)gridDim.x * blockDim.x;
  const float4* x4 = (const float4*)x;
  size_t n4 = n >> 2;
  for (size_t i = tid0; i < n4; i += stride) {
    float4 v = x4[i];
    ushort4 o;
    o.x = f32_to_bf16(__expf(v.x));
    o.y = f32_to_bf16(__expf(v.y));
    o.z = f32_to_bf16(__expf(v.z));
    o.w = f32_to_bf16(__expf(v.w));
    ((ushort4*)y)[i] = o;
  }
}

// ------------- exp(w) -> bf16, transposed: Bt[n][d] -------------
__global__ void expcvt_wt_kernel(const float* __restrict__ w,
                                 unsigned short* __restrict__ bt,
                                 int D, int O) {
  __shared__ unsigned short tile[32][33];
  int c0 = blockIdx.x * 32;   // O (col of w)
  int r0 = blockIdx.y * 32;   // D (row of w)
  int tx = threadIdx.x;       // 0..31
  int ty = threadIdx.y;       // 0..7
#pragma unroll
  for (int j = 0; j < 4; ++j) {
    int r = r0 + ty + j * 8;
    tile[ty + j * 8][tx] = f32_to_bf16(__expf(w[(size_t)r * O + c0 + tx]));
  }
  __syncthreads();
#pragma unroll
  for (int j = 0; j < 4; ++j) {
    int outr = c0 + ty + j * 8;            // N index
    bt[(size_t)outr * D + r0 + tx] = tile[tx][ty + j * 8];
  }
}

// ---------------- 256x256 8-phase bf16 MFMA GEMM, log+bias epilogue ----------------
// A   : [M][K] bf16 (exp_inputs)     Bt : [N][K] bf16 (exp_w transposed)
// out : [M][N] f32 = log(A@B) + bias[n]
// 512 threads = 8 waves (2 Mrow x 4 Ncol), per-wave C tile 128x64.
// LDS 128 KiB: slot s (s = tile&1): A at s*65536 (2 halves of 16KB), B at +32768.
// XOR swizzle: colb ^= (row&7)<<4 (involution; applied on pre-swizzled
// global_load_lds source AND on ds_read addresses).
// Deep pipeline: stages land 4-7 phases ahead; vmcnt(4)@P4, vmcnt(6)@P8.

#define LOAD_A4(PTR, MOFF)                                                  \
  _Pragma("unroll") for (int mm = 0; mm < 4; ++mm) {                        \
    aF[mm][0] = *(const bf16x8v*)((PTR) + (MOFF + mm) * 2048 + cb0);        \
    aF[mm][1] = *(const bf16x8v*)((PTR) + (MOFF + mm) * 2048 + cb1);        \
  }
#define LOAD_B2(DST, PTR, NOFF)                                             \
  _Pragma("unroll") for (int nn = 0; nn < 2; ++nn) {                        \
    DST[nn][0] = *(const bf16x8v*)((PTR) + (NOFF + nn) * 2048 + cb0);       \
    DST[nn][1] = *(const bf16x8v*)((PTR) + (NOFF + nn) * 2048 + cb1);       \
  }
#define MFMA_Q(MB, NB, BARR)                                                \
  _Pragma("unroll") for (int mm = 0; mm < 4; ++mm)                          \
  _Pragma("unroll") for (int nn = 0; nn < 2; ++nn)                          \
  _Pragma("unroll") for (int ks = 0; ks < 2; ++ks)                          \
    acc[MB + mm][NB + nn] = __builtin_amdgcn_mfma_f32_16x16x32_bf16(        \
        aF[mm][ks], BARR[nn][ks], acc[MB + mm][NB + nn], 0, 0, 0);

__global__ __launch_bounds__(512, 2) void gemm8_log_kernel(
    const unsigned short* __restrict__ A, const unsigned short* __restrict__ Bt,
    const float* __restrict__ bias, float* __restrict__ out,
    int M, int N, int K) {
  __shared__ char lds[131072];

  const int tid  = threadIdx.x;
  const int wid  = tid >> 6, lane = tid & 63;
  const int wr   = wid >> 2, wc = wid & 3;
  const int r    = lane & 15, lh = lane >> 4;
  const int NT   = K >> 6;        // number of 64-wide K tiles (32)
  const int NIT  = NT >> 1;       // iterations (2 tiles each)
  const size_t Kb = (size_t)K * 2;

  // XCD-aware bijective swizzle (gridDim.x % 8 == 0 here: 512)
  const int cpx = gridDim.x >> 3;
  const int v   = (blockIdx.x & 7) * cpx + (blockIdx.x >> 3);
  const int nbn = N >> 8;
  const int bm  = v / nbn, bn = v % nbn;
  const int brow = bm << 8, bcol = bn << 8;

  // swizzled column-byte offsets for ds_read_b128 (row&7 == r&7 always)
  const int swz = (r & 7) << 4;
  const int cb0 = (lh * 16) ^ swz;        // ks = 0
  const int cb1 = cb0 ^ 64;               // ks = 1

  const char* pA0 = lds + wr * 16384 + r * 128;
  const char* pA1 = pA0 + 65536;
  const char* pB0 = lds + 32768 + (wc >> 1) * 16384 + ((wc & 1) * 64 + r) * 128;
  const char* pB1 = pB0 + 65536;

  // stage one 16KB half-tile (2 x global_load_lds of 16B x 512 threads)
  auto STAGE = [&](int t, int isB, int h) {
    const int tt = (t < NT) ? t : NT - 1;     // clamp keeps vmcnt ledger uniform
    const char* src = isB ? (const char*)Bt : (const char*)A;
    const int g0 = (isB ? bcol : brow) + h * 128;
    char* base = lds + (t & 1) * 65536 + isB * 32768 + h * 16384;
#pragma unroll
    for (int i = 0; i < 2; ++i) {
      const int o    = i * 8192 + tid * 16;
      const int row  = o >> 7;
      const int colb = (o & 127) ^ ((row & 7) << 4);   // inverse-swizzled source
      const char* g  = src + (size_t)(g0 + row) * Kb + (size_t)tt * 128 + colb;
      char* dst = base + i * 8192 + (tid >> 6) * 1024;  // wave-uniform base
      __builtin_amdgcn_global_load_lds(GLOBAL_AS(g), LDS_AS(dst), 16, 0, 0);
    }
  };

  f32x4 acc[8][4];
#pragma unroll
  for (int m = 0; m < 8; ++m)
#pragma unroll
    for (int n = 0; n < 4; ++n) acc[m][n] = (f32x4)0.0f;

  bf16x8v aF[4][2], b01[2][2], b23[2][2];

  // prologue: tile0 fully + tile1 {Bh0, Ah0, Ah1}  (7 half-tiles = 14 loads)
  STAGE(0, 1, 0); STAGE(0, 0, 0); STAGE(0, 0, 1); STAGE(0, 1, 1);
  STAGE(1, 1, 0); STAGE(1, 0, 0); STAGE(1, 0, 1);
  VMCNT(6);   // retire tile0's 8 loads; keep tile1's 3 half-tiles in flight
  BAR();

  for (int j = 0; j < NIT; ++j) {
    const int t1 = 2 * j + 1, t2 = 2 * j + 2, t3 = 2 * j + 3;
    // -- P1 (slot0): read A m0-3 + B n0-1; stage Bh1(t1); Q(0,0)
    LOAD_A4(pA0, 0)
    LOAD_B2(b01, pB0, 0)
    STAGE(t1, 1, 1);
    BAR(); LGKM0();
    SP1 MFMA_Q(0, 0, b01) SP0
    BAR();
    // -- P2: read B n2-3; Q(0,1)
    LOAD_B2(b23, pB0, 2)
    BAR(); LGKM0();
    SP1 MFMA_Q(0, 2, b23) SP0
    BAR();
    // -- P3: read A m4-7; stage Bh0(t2); Q(1,1)
    LOAD_A4(pA0, 4)
    STAGE(t2, 1, 0);
    BAR(); LGKM0();
    SP1 MFMA_Q(4, 2, b23) SP0
    BAR();
    // -- P4: stage Ah0(t2); vmcnt(4) -> tile t1 fully resident; Q(1,0) from regs
    STAGE(t2, 0, 0);
    VMCNT(4);
    BAR();
    SP1 MFMA_Q(4, 0, b01) SP0
    BAR();
    // -- P5 (slot1): read A m0-3 + B n0-1; stage Ah1(t2); Q(0,0)
    LOAD_A4(pA1, 0)
    LOAD_B2(b01, pB1, 0)
    STAGE(t2, 0, 1);
    BAR(); LGKM0();
    SP1 MFMA_Q(0, 0, b01) SP0
    BAR();
    // -- P6: read B n2-3; stage Bh1(t2); Q(0,1)
    LOAD_B2(b23, pB1, 2)
    STAGE(t2, 1, 1);
    BAR(); LGKM0();
    SP1 MFMA_Q(0, 2, b23) SP0
    BAR();
    // -- P7: read A m4-7; stage Bh0(t3); Q(1,1)
    LOAD_A4(pA1, 4)
    STAGE(t3, 1, 0);
    BAR(); LGKM0();
    SP1 MFMA_Q(4, 2, b23) SP0
    BAR();
    // -- P8: stage Ah0(t3)+Ah1(t3); vmcnt(6) -> tile t2 fully resident; Q(1,0)
    STAGE(t3, 0, 0);
    STAGE(t3, 0, 1);
    VMCNT(6);
    BAR();
    SP1 MFMA_Q(4, 0, b01) SP0
    BAR();
  }

  VMCNT(0);

  // epilogue: out = log(acc) + bias  (n innermost: 4 consecutive 64B segments
  // per 256B row-span -> TCC write-combining)
  const int crow0 = brow + wr * 128 + lh * 4;
  const int ccol0 = bcol + wc * 64 + r;
  float bvs[4];
#pragma unroll
  for (int n = 0; n < 4; ++n) bvs[n] = bias[ccol0 + n * 16];
#pragma unroll
  for (int m = 0; m < 8; ++m) {
    const int rowb = crow0 + m * 16;
#pragma unroll
    for (int q = 0; q < 4; ++q) {
      const size_t ro = (size_t)(rowb + q) * N + ccol0;
#pragma unroll
      for (int n = 0; n < 4; ++n)
        out[ro + n * 16] = __logf(acc[m][n][q]) + bvs[n];
    }
  }
}

extern "C" void kernel_launch(void* const* d_in, const int* in_sizes, int n_in,
                              void* d_out, int out_size, void* d_ws, size_t ws_size,
                              hipStream_t stream) {
  const float* inputs = (const float*)d_in[0];
  const float* w      = (const float*)d_in[1];
  const float* bias   = (const float*)d_in[2];
  float* out = (float*)d_out;

  const int O = in_sizes[2];                 // 2048
  const int D = in_sizes[1] / O;             // 2048
  const size_t MD = (size_t)in_sizes[0];     // M*D
  const int M = (int)(MD / (size_t)D);       // 16384

  unsigned short* Abf  = (unsigned short*)d_ws;
  unsigned short* Btbf = (unsigned short*)((char*)d_ws + MD * 2);

  expcvt_a_kernel<<<2048, 256, 0, stream>>>(inputs, Abf, MD);

  dim3 tg(O / 32, D / 32);
  expcvt_wt_kernel<<<tg, dim3(32, 8), 0, stream>>>(w, Btbf, D, O);

  dim3 grid((M / 256) * (O / 256));
  gemm8_log_kernel<<<grid, 512, 0, stream>>>(Abf, Btbf, bias, out, M, O, D);
}

// Round 4
// 167.733 us; speedup vs baseline: 1.5539x; 1.0217x over previous
//
#include <hip/hip_runtime.h>

typedef short  bf16x8v __attribute__((ext_vector_type(8)));
typedef float  f32x4   __attribute__((ext_vector_type(4)));

#define GLOBAL_AS(p) ((const __attribute__((address_space(1))) void*)(p))
#define LDS_AS(p)    ((__attribute__((address_space(3))) void*)(p))
#define BAR()     __builtin_amdgcn_s_barrier()
#define VMCNT(n)  asm volatile("s_waitcnt vmcnt(" #n ")" ::: "memory")
#define SP1       __builtin_amdgcn_s_setprio(1);
#define SP0       __builtin_amdgcn_s_setprio(0);

__device__ inline unsigned short f32_to_bf16(float f) {
  unsigned u = __float_as_uint(f);
  unsigned r = (u + 0x7FFFu + ((u >> 16) & 1u)) >> 16;
  return (unsigned short)r;
}

// ---------------- exp(x) -> bf16, contiguous [M][K] ----------------
__global__ void expcvt_a_kernel(const float* __restrict__ x,
                                unsigned short* __restrict__ y, size_t n) {
  size_t tid0   = (size_t)blockIdx.x * blockDim.x + threadIdx.x;
  size_t stride = (size_t)gridDim.x * blockDim.x;
  const float4* x4 = (const float4*)x;
  size_t n4 = n >> 2;
  for (size_t i = tid0; i < n4; i += stride) {
    float4 v = x4[i];
    ushort4 o;
    o.x = f32_to_bf16(__expf(v.x));
    o.y = f32_to_bf16(__expf(v.y));
    o.z = f32_to_bf16(__expf(v.z));
    o.w = f32_to_bf16(__expf(v.w));
    ((ushort4*)y)[i] = o;
  }
}

// ------------- exp(w) -> bf16, transposed: Bt[n][d] -------------
__global__ void expcvt_wt_kernel(const float* __restrict__ w,
                                 unsigned short* __restrict__ bt,
                                 int D, int O) {
  __shared__ unsigned short tile[32][33];
  int c0 = blockIdx.x * 32;   // O (col of w)
  int r0 = blockIdx.y * 32;   // D (row of w)
  int tx = threadIdx.x;       // 0..31
  int ty = threadIdx.y;       // 0..7
#pragma unroll
  for (int j = 0; j < 4; ++j) {
    int r = r0 + ty + j * 8;
    tile[ty + j * 8][tx] = f32_to_bf16(__expf(w[(size_t)r * O + c0 + tx]));
  }
  __syncthreads();
#pragma unroll
  for (int j = 0; j < 4; ++j) {
    int outr = c0 + ty + j * 8;            // N index
    bt[(size_t)outr * D + r0 + tx] = tile[tx][ty + j * 8];
  }
}

// ---------------- 256x256 8-phase bf16 MFMA GEMM, log+bias epilogue ----------------
// Lag-1 read schedule: each phase's fragments are ds_read at the END of the
// previous phase (right after the MFMA cluster that last read those regs).
// One barrier per phase (10/iter incl. the 2 vmcnt barriers).
// Stages: P1:Bh1(t1) P4:Bh0+Ah0(t2) P5:Ah1(t2) P6:Bh1(t2) P8:Ah0+Ah1+Bh0(t3).
// vmcnt(4)@P4 validates slot1(t1); vmcnt(6)@P8 validates slot0(t2).
// Every LDS region has >=1 barrier between last-read-completion and re-stage.

#define LOAD_A4(PTR, MOFF)                                                  \
  _Pragma("unroll") for (int mm = 0; mm < 4; ++mm) {                        \
    aF[mm][0] = *(const bf16x8v*)((PTR) + (MOFF + mm) * 2048 + cb0);        \
    aF[mm][1] = *(const bf16x8v*)((PTR) + (MOFF + mm) * 2048 + cb1);        \
  }
#define LOAD_B2(DST, PTR, NOFF)                                             \
  _Pragma("unroll") for (int nn = 0; nn < 2; ++nn) {                        \
    DST[nn][0] = *(const bf16x8v*)((PTR) + (NOFF + nn) * 2048 + cb0);       \
    DST[nn][1] = *(const bf16x8v*)((PTR) + (NOFF + nn) * 2048 + cb1);       \
  }
#define MFMA_Q(MB, NB, BARR)                                                \
  _Pragma("unroll") for (int mm = 0; mm < 4; ++mm)                          \
  _Pragma("unroll") for (int nn = 0; nn < 2; ++nn)                          \
  _Pragma("unroll") for (int ks = 0; ks < 2; ++ks)                          \
    acc[MB + mm][NB + nn] = __builtin_amdgcn_mfma_f32_16x16x32_bf16(        \
        aF[mm][ks], BARR[nn][ks], acc[MB + mm][NB + nn], 0, 0, 0);

__global__ __launch_bounds__(512, 2) void gemm8_log_kernel(
    const unsigned short* __restrict__ A, const unsigned short* __restrict__ Bt,
    const float* __restrict__ bias, float* __restrict__ out,
    int M, int N, int K) {
  __shared__ char lds[131072];

  const int tid  = threadIdx.x;
  const int wid  = tid >> 6, lane = tid & 63;
  const int wr   = wid >> 2, wc = wid & 3;
  const int r    = lane & 15, lh = lane >> 4;
  const int NT   = K >> 6;        // number of 64-wide K tiles (32)
  const int NIT  = NT >> 1;       // iterations (2 tiles each)
  const size_t Kb = (size_t)K * 2;

  // XCD-aware bijective swizzle (gridDim.x % 8 == 0 here: 512)
  const int cpx = gridDim.x >> 3;
  const int v   = (blockIdx.x & 7) * cpx + (blockIdx.x >> 3);
  const int nbn = N >> 8;
  const int bm  = v / nbn, bn = v % nbn;
  const int brow = bm << 8, bcol = bn << 8;

  // swizzled column-byte offsets for ds_read_b128 (row&7 == r&7 always)
  const int swz = (r & 7) << 4;
  const int cb0 = (lh * 16) ^ swz;        // ks = 0
  const int cb1 = cb0 ^ 64;               // ks = 1

  const char* pA0 = lds + wr * 16384 + r * 128;
  const char* pA1 = pA0 + 65536;
  const char* pB0 = lds + 32768 + (wc >> 1) * 16384 + ((wc & 1) * 64 + r) * 128;
  const char* pB1 = pB0 + 65536;

  // stage one 16KB half-tile (2 x global_load_lds of 16B x 512 threads)
  auto STAGE = [&](int t, int isB, int h) {
    const int tt = (t < NT) ? t : NT - 1;     // clamp keeps vmcnt ledger uniform
    const char* src = isB ? (const char*)Bt : (const char*)A;
    const int g0 = (isB ? bcol : brow) + h * 128;
    char* base = lds + (t & 1) * 65536 + isB * 32768 + h * 16384;
#pragma unroll
    for (int i = 0; i < 2; ++i) {
      const int o    = i * 8192 + tid * 16;
      const int row  = o >> 7;
      const int colb = (o & 127) ^ ((row & 7) << 4);   // inverse-swizzled source
      const char* g  = src + (size_t)(g0 + row) * Kb + (size_t)tt * 128 + colb;
      char* dst = base + i * 8192 + (tid >> 6) * 1024;  // wave-uniform base
      __builtin_amdgcn_global_load_lds(GLOBAL_AS(g), LDS_AS(dst), 16, 0, 0);
    }
  };

  f32x4 acc[8][4];
#pragma unroll
  for (int m = 0; m < 8; ++m)
#pragma unroll
    for (int n = 0; n < 4; ++n) acc[m][n] = (f32x4)0.0f;

  bf16x8v aF[4][2], b01[2][2], b23[2][2];

  // prologue: t0 fully (Bh0,Ah0,Ah1,Bh1 = 8 loads) + t1 {Ah0,Ah1,Bh0} (6 loads)
  STAGE(0, 1, 0); STAGE(0, 0, 0); STAGE(0, 0, 1); STAGE(0, 1, 1);
  STAGE(1, 0, 0); STAGE(1, 0, 1); STAGE(1, 1, 0);
  VMCNT(6);   // t0 resident; t1's 3 half-tiles stay in flight
  BAR();
  LOAD_A4(pA0, 0)         // A0(t0)
  LOAD_B2(b01, pB0, 0)    // B01(t0)

  for (int j = 0; j < NIT; ++j) {
    const int t1 = 2 * j + 1, t2 = 2 * j + 2, t3 = 2 * j + 3;
    // -- P1: stage Bh1(t1)->s1; Q(0,0)=A0xB01; rd B23(s0)
    STAGE(t1, 1, 1);
    SP1 MFMA_Q(0, 0, b01) SP0
    LOAD_B2(b23, pB0, 2)
    BAR();
    // -- P2: Q(0,1)=A0xB23; rd A1(s0) (aF dead after MFMA)
    SP1 MFMA_Q(0, 2, b23) SP0
    LOAD_A4(pA0, 4)
    BAR();
    // -- P3: Q(1,1)=A1xB23
    SP1 MFMA_Q(4, 2, b23) SP0
    BAR();
    // -- P4: stage Bh0(t2)+Ah0(t2)->s0; vmcnt(4) -> t1 resident; barrier;
    //        Q(1,0)=A1xB01; rd A0'(s1)+B01'(s1)
    STAGE(t2, 1, 0); STAGE(t2, 0, 0);
    VMCNT(4);
    BAR();
    SP1 MFMA_Q(4, 0, b01) SP0
    LOAD_A4(pA1, 0)
    LOAD_B2(b01, pB1, 0)
    BAR();
    // -- P5: stage Ah1(t2); Q(0,0)'=A0'xB01'; rd B23'(s1)
    STAGE(t2, 0, 1);
    SP1 MFMA_Q(0, 0, b01) SP0
    LOAD_B2(b23, pB1, 2)
    BAR();
    // -- P6: stage Bh1(t2); Q(0,1)'=A0'xB23'; rd A1'(s1)
    STAGE(t2, 1, 1);
    SP1 MFMA_Q(0, 2, b23) SP0
    LOAD_A4(pA1, 4)
    BAR();
    // -- P7: Q(1,1)'=A1'xB23'
    SP1 MFMA_Q(4, 2, b23) SP0
    BAR();
    // -- P8: stage Ah0+Ah1+Bh0(t3)->s1; vmcnt(6) -> t2 resident; barrier;
    //        Q(1,0)'=A1'xB01'; rd A0(next,s0)+B01(next,s0)
    STAGE(t3, 0, 0); STAGE(t3, 0, 1); STAGE(t3, 1, 0);
    VMCNT(6);
    BAR();
    SP1 MFMA_Q(4, 0, b01) SP0
    LOAD_A4(pA0, 0)
    LOAD_B2(b01, pB0, 0)
    BAR();
  }

  VMCNT(0);

  // epilogue: out = log(acc) + bias  (n innermost: 4 consecutive 64B segments
  // per 256B row-span -> TCC write-combining)
  const int crow0 = brow + wr * 128 + lh * 4;
  const int ccol0 = bcol + wc * 64 + r;
  float bvs[4];
#pragma unroll
  for (int n = 0; n < 4; ++n) bvs[n] = bias[ccol0 + n * 16];
#pragma unroll
  for (int m = 0; m < 8; ++m) {
    const int rowb = crow0 + m * 16;
#pragma unroll
    for (int q = 0; q < 4; ++q) {
      const size_t ro = (size_t)(rowb + q) * N + ccol0;
#pragma unroll
      for (int n = 0; n < 4; ++n)
        out[ro + n * 16] = __logf(acc[m][n][q]) + bvs[n];
    }
  }
}

extern "C" void kernel_launch(void* const* d_in, const int* in_sizes, int n_in,
                              void* d_out, int out_size, void* d_ws, size_t ws_size,
                              hipStream_t stream) {
  const float* inputs = (const float*)d_in[0];
  const float* w      = (const float*)d_in[1];
  const float* bias   = (const float*)d_in[2];
  float* out = (float*)d_out;

  const int O = in_sizes[2];                 // 2048
  const int D = in_sizes[1] / O;             // 2048
  const size_t MD = (size_t)in_sizes[0];     // M*D
  const int M = (int)(MD / (size_t)D);       // 16384

  unsigned short* Abf  = (unsigned short*)d_ws;
  unsigned short* Btbf = (unsigned short*)((char*)d_ws + MD * 2);

  expcvt_a_kernel<<<2048, 256, 0, stream>>>(inputs, Abf, MD);

  dim3 tg(O / 32, D / 32);
  expcvt_wt_kernel<<<tg, dim3(32, 8), 0, stream>>>(w, Btbf, D, O);

  dim3 grid((M / 256) * (O / 256));
  gemm8_log_kernel<<<grid, 512, 0, stream>>>(Abf, Btbf, bias, out, M, O, D);
}

// Round 5
// 121.242 us; speedup vs baseline: 2.1497x; 1.3835x over previous
//
#include <hip/hip_runtime.h>

typedef int   i32x4v __attribute__((ext_vector_type(4)));
typedef int   i32x8v __attribute__((ext_vector_type(8)));
typedef float f32x16 __attribute__((ext_vector_type(16)));

#define GLOBAL_AS(p) ((const __attribute__((address_space(1))) void*)(p))
#define LDS_AS(p)    ((__attribute__((address_space(3))) void*)(p))
#define BAR()     __builtin_amdgcn_s_barrier()
#define VMCNT(n)  asm volatile("s_waitcnt vmcnt(" #n ")" ::: "memory")
#define SP1       __builtin_amdgcn_s_setprio(1);
#define SP0       __builtin_amdgcn_s_setprio(0);

// ---------------- exp(x) -> fp8 e4m3, contiguous [M][K] ----------------
__global__ void expcvt_a8_kernel(const float* __restrict__ x,
                                 unsigned* __restrict__ y, size_t n8) {
  size_t tid0   = (size_t)blockIdx.x * blockDim.x + threadIdx.x;
  size_t stride = (size_t)gridDim.x * blockDim.x;
  const float4* x4 = (const float4*)x;
  for (size_t i = tid0; i < n8; i += stride) {
    float4 v0 = x4[2 * i], v1 = x4[2 * i + 1];
    int lo = 0, hi = 0;
    lo = __builtin_amdgcn_cvt_pk_fp8_f32(__expf(v0.x), __expf(v0.y), lo, false);
    lo = __builtin_amdgcn_cvt_pk_fp8_f32(__expf(v0.z), __expf(v0.w), lo, true);
    hi = __builtin_amdgcn_cvt_pk_fp8_f32(__expf(v1.x), __expf(v1.y), hi, false);
    hi = __builtin_amdgcn_cvt_pk_fp8_f32(__expf(v1.z), __expf(v1.w), hi, true);
    ((uint2*)y)[i] = make_uint2((unsigned)lo, (unsigned)hi);
  }
}

// ------------- exp(w) -> fp8 e4m3, transposed: Bt[n][d] -------------
__global__ void expcvt_wt8_kernel(const float* __restrict__ w,
                                  unsigned char* __restrict__ bt,
                                  int D, int O) {
  __shared__ unsigned char tile[32][33];
  int c0 = blockIdx.x * 32;   // O (col of w)
  int r0 = blockIdx.y * 32;   // D (row of w)
  int tx = threadIdx.x;       // 0..31
  int ty = threadIdx.y;       // 0..7
#pragma unroll
  for (int j = 0; j < 4; ++j) {
    int r = r0 + ty + j * 8;
    float e = __expf(w[(size_t)r * O + c0 + tx]);
    int p = __builtin_amdgcn_cvt_pk_fp8_f32(e, e, 0, false);
    tile[ty + j * 8][tx] = (unsigned char)(p & 0xFF);
  }
  __syncthreads();
  int t    = ty * 32 + tx;     // 0..255
  int orow = t >> 3;           // 0..31  (O index within tile)
  int b4   = (t & 7) * 4;      // 4-byte group along D
  unsigned u = (unsigned)tile[b4][orow] | ((unsigned)tile[b4 + 1][orow] << 8) |
               ((unsigned)tile[b4 + 2][orow] << 16) |
               ((unsigned)tile[b4 + 3][orow] << 24);
  *(unsigned*)(bt + (size_t)(c0 + orow) * D + r0 + b4) = u;
}

// ------------- 256x256 8-phase MX-fp8 MFMA GEMM, log+bias epilogue -------------
// A  : [M][K] fp8 (exp_inputs)    Bt : [N][K] fp8 (exp_w transposed)
// out: [M][N] f32 = log(A@B) + bias[n]
// 512 thr = 8 waves (2 Mrow x 4 Ncol), per-wave C 128x64 = 4mb x 2nb of 32x32.
// K-tile = 128 fp8 bytes -> A tile 256x128B = 32KB (= bf16 version), so the
// LDS layout / STAGE / vmcnt ledger / swizzle carry over identically.
// MFMA: mfma_scale_f32_32x32x64_f8f6f4, fp8/fp8, unit scales (0x7F7F7F7F).
// Fragment: lane holds row=lane&31, k=(lane>>5)*32 + j (32B = two b128,
// swizzled offsets XOR 16/64/80).

#define FR(P, C0, C1)                                                       \
  __builtin_shufflevector(*(const i32x4v*)((P) + (C0)),                     \
                          *(const i32x4v*)((P) + (C1)), 0, 1, 2, 3, 4, 5, 6, 7)

#define LOAD_A(PTR, MH)                                                     \
  aF[0][0] = FR((PTR) + ((MH)*2 + 0) * 4096, c00, c01);                     \
  aF[0][1] = FR((PTR) + ((MH)*2 + 0) * 4096, c10, c11);                     \
  aF[1][0] = FR((PTR) + ((MH)*2 + 1) * 4096, c00, c01);                     \
  aF[1][1] = FR((PTR) + ((MH)*2 + 1) * 4096, c10, c11);

#define LOAD_B(DST, PTR, NB)                                                \
  DST[0] = FR((PTR) + (NB)*4096, c00, c01);                                 \
  DST[1] = FR((PTR) + (NB)*4096, c10, c11);

#define MFMA_Q(MH, NB, BF)                                                  \
  _Pragma("unroll") for (int mm = 0; mm < 2; ++mm)                          \
  _Pragma("unroll") for (int ks = 0; ks < 2; ++ks)                          \
    acc[(MH)*2 + mm][NB] = __builtin_amdgcn_mfma_scale_f32_32x32x64_f8f6f4( \
        aF[mm][ks], BF[ks], acc[(MH)*2 + mm][NB], 0, 0,                     \
        0, 0x7F7F7F7F, 0, 0x7F7F7F7F);

__global__ __launch_bounds__(512, 2) void gemm8mx_log_kernel(
    const unsigned char* __restrict__ A, const unsigned char* __restrict__ Bt,
    const float* __restrict__ bias, float* __restrict__ out,
    int M, int N, int K) {
  __shared__ char lds[131072];

  const int tid  = threadIdx.x;
  const int wid  = tid >> 6, lane = tid & 63;
  const int wr   = wid >> 2, wc = wid & 3;
  const int l31  = lane & 31, lk = lane >> 5;
  const int NT   = K >> 7;        // 128B K-tiles (16)
  const int NIT  = NT >> 1;       // iterations (8)
  const size_t Kb = (size_t)K;    // bytes per row (fp8)

  // XCD-aware bijective swizzle (gridDim.x % 8 == 0 here: 512)
  const int cpx = gridDim.x >> 3;
  const int v   = (blockIdx.x & 7) * cpx + (blockIdx.x >> 3);
  const int nbn = N >> 8;
  const int bm  = v / nbn, bn = v % nbn;
  const int brow = bm << 8, bcol = bn << 8;

  // swizzled fragment byte offsets: base = ks*64 + lk*32 + i*16, XOR (l31&7)<<4
  const int swz = (l31 & 7) << 4;
  const int c00 = (lk * 32) ^ swz;
  const int c01 = c00 ^ 16;
  const int c10 = c00 ^ 64;
  const int c11 = c00 ^ 80;

  const char* pA0 = lds + wr * 16384 + l31 * 128;
  const char* pA1 = pA0 + 65536;
  const char* pB0 = lds + 32768 + (wc >> 1) * 16384 + ((wc & 1) * 64 + l31) * 128;
  const char* pB1 = pB0 + 65536;

  // stage one 16KB half-tile (2 x global_load_lds of 16B x 512 threads)
  auto STAGE = [&](int t, int isB, int h) {
    const int tt = (t < NT) ? t : NT - 1;     // clamp keeps vmcnt ledger uniform
    const char* src = isB ? (const char*)Bt : (const char*)A;
    const int g0 = (isB ? bcol : brow) + h * 128;
    char* base = lds + (t & 1) * 65536 + isB * 32768 + h * 16384;
#pragma unroll
    for (int i = 0; i < 2; ++i) {
      const int o    = i * 8192 + tid * 16;
      const int row  = o >> 7;
      const int colb = (o & 127) ^ ((row & 7) << 4);   // inverse-swizzled source
      const char* g  = src + (size_t)(g0 + row) * Kb + (size_t)tt * 128 + colb;
      char* dst = base + i * 8192 + (tid >> 6) * 1024;  // wave-uniform base
      __builtin_amdgcn_global_load_lds(GLOBAL_AS(g), LDS_AS(dst), 16, 0, 0);
    }
  };

  f32x16 acc[4][2];
#pragma unroll
  for (int m = 0; m < 4; ++m)
#pragma unroll
    for (int n = 0; n < 2; ++n) acc[m][n] = (f32x16)0.0f;

  i32x8v aF[2][2], bF0[2], bF1[2];

  // prologue: t0 fully + t1 {Ah0, Ah1, Bh0}  (7 half-tiles = 14 loads)
  STAGE(0, 1, 0); STAGE(0, 0, 0); STAGE(0, 0, 1); STAGE(0, 1, 1);
  STAGE(1, 0, 0); STAGE(1, 0, 1); STAGE(1, 1, 0);
  VMCNT(6);   // t0 resident; t1's 3 half-tiles stay in flight
  BAR();
  LOAD_A(pA0, 0)          // A mh0 (t0)
  LOAD_B(bF0, pB0, 0)     // B nb0 (t0)

  for (int j = 0; j < NIT; ++j) {
    const int t1 = 2 * j + 1, t2 = 2 * j + 2, t3 = 2 * j + 3;
    // -- P1: stage Bh1(t1)->s1; Q(mh0,nb0); rd bF1(s0)
    STAGE(t1, 1, 1);
    SP1 MFMA_Q(0, 0, bF0) SP0
    LOAD_B(bF1, pB0, 1)
    BAR();
    // -- P2: Q(mh0,nb1); rd A mh1 (aF dead after MFMA)
    SP1 MFMA_Q(0, 1, bF1) SP0
    LOAD_A(pA0, 1)
    BAR();
    // -- P3: Q(mh1,nb1)
    SP1 MFMA_Q(1, 1, bF1) SP0
    BAR();
    // -- P4: stage Bh0(t2)+Ah0(t2)->s0; vmcnt(4) -> t1 resident; barrier;
    //        Q(mh1,nb0); rd A mh0(s1) + bF0(s1)
    STAGE(t2, 1, 0); STAGE(t2, 0, 0);
    VMCNT(4);
    BAR();
    SP1 MFMA_Q(1, 0, bF0) SP0
    LOAD_A(pA1, 0)
    LOAD_B(bF0, pB1, 0)
    BAR();
    // -- P5: stage Ah1(t2); Q(mh0,nb0)'; rd bF1(s1)
    STAGE(t2, 0, 1);
    SP1 MFMA_Q(0, 0, bF0) SP0
    LOAD_B(bF1, pB1, 1)
    BAR();
    // -- P6: stage Bh1(t2); Q(mh0,nb1)'; rd A mh1(s1)
    STAGE(t2, 1, 1);
    SP1 MFMA_Q(0, 1, bF1) SP0
    LOAD_A(pA1, 1)
    BAR();
    // -- P7: Q(mh1,nb1)'
    SP1 MFMA_Q(1, 1, bF1) SP0
    BAR();
    // -- P8: stage Ah0+Ah1+Bh0(t3)->s1; vmcnt(6) -> t2 resident; barrier;
    //        Q(mh1,nb0)'; rd A mh0(next,s0) + bF0(next,s0)
    STAGE(t3, 0, 0); STAGE(t3, 0, 1); STAGE(t3, 1, 0);
    VMCNT(6);
    BAR();
    SP1 MFMA_Q(1, 0, bF0) SP0
    LOAD_A(pA0, 0)
    LOAD_B(bF0, pB0, 0)
    BAR();
  }

  VMCNT(0);

  // epilogue: out = log(acc) + bias
  // 32x32 C/D layout: col = lane&31, row = (reg&3) + 8*(reg>>2) + 4*(lane>>5)
  const int col0 = bcol + wc * 64 + l31;
  const int row0 = brow + wr * 128 + lk * 4;
  const float bv0 = bias[col0], bv1 = bias[col0 + 32];
#pragma unroll
  for (int mb = 0; mb < 4; ++mb) {
#pragma unroll
    for (int rg = 0; rg < 16; ++rg) {
      const int row = row0 + mb * 32 + (rg & 3) + 8 * (rg >> 2);
      const size_t ro = (size_t)row * N + col0;
      out[ro]      = __logf(acc[mb][0][rg]) + bv0;
      out[ro + 32] = __logf(acc[mb][1][rg]) + bv1;
    }
  }
}

extern "C" void kernel_launch(void* const* d_in, const int* in_sizes, int n_in,
                              void* d_out, int out_size, void* d_ws, size_t ws_size,
                              hipStream_t stream) {
  const float* inputs = (const float*)d_in[0];
  const float* w      = (const float*)d_in[1];
  const float* bias   = (const float*)d_in[2];
  float* out = (float*)d_out;

  const int O = in_sizes[2];                 // 2048
  const int D = in_sizes[1] / O;             // 2048
  const size_t MD = (size_t)in_sizes[0];     // M*D
  const int M = (int)(MD / (size_t)D);       // 16384

  unsigned char* A8  = (unsigned char*)d_ws;
  unsigned char* Bt8 = (unsigned char*)d_ws + MD;

  expcvt_a8_kernel<<<2048, 256, 0, stream>>>(inputs, (unsigned*)A8, MD / 8);

  dim3 tg(O / 32, D / 32);
  expcvt_wt8_kernel<<<tg, dim3(32, 8), 0, stream>>>(w, Bt8, D, O);

  dim3 grid((M / 256) * (O / 256));
  gemm8mx_log_kernel<<<grid, 512, 0, stream>>>(A8, Bt8, bias, out, M, O, D);
}